// Round 3
// baseline (329.837 us; speedup 1.0000x reference)
//
#include <hip/hip_runtime.h>

#define NNODES 50000
#define NEDGES 800000
#define DIN 128
#define DHID 128
#define DOUT 64

// ---- bf16 helpers ---------------------------------------------------------
static __device__ __forceinline__ unsigned short f2bf(float f) {
  union { float f; unsigned u; } v; v.f = f;
  unsigned r = v.u + 0x7fffu + ((v.u >> 16) & 1u);  // round-nearest-even
  return (unsigned short)(r >> 16);
}
static __device__ __forceinline__ float bf_lo(unsigned v) {
  union { unsigned u; float f; } t; t.u = v << 16; return t.f;
}
static __device__ __forceinline__ float bf_hi(unsigned v) {
  union { unsigned u; float f; } t; t.u = v & 0xffff0000u; return t.f;
}
static __device__ __forceinline__ float bf1(unsigned short v) {
  union { unsigned u; float f; } t; t.u = ((unsigned)v) << 16; return t.f;
}

// ---------------------------------------------------------------------------
// Pass 1: degree count + per-edge slot (dense write by edge index -> no
// scattered partial-line writeback traffic).
// ---------------------------------------------------------------------------
__global__ __launch_bounds__(256) void count_kernel(
    const int* __restrict__ dst, int* __restrict__ deg,
    int* __restrict__ slot, int E) {
  int e = blockIdx.x * 256 + threadIdx.x;
  if (e >= E) return;
  slot[e] = atomicAdd(&deg[dst[e]], 1);
}

// ---------------------------------------------------------------------------
// Pass 2: single-block exclusive scan of deg -> rowptr[N+1].
// 1024 threads, ~49 nodes per thread, Hillis-Steele over partials in LDS.
// ---------------------------------------------------------------------------
__global__ __launch_bounds__(1024) void scan_kernel(
    const int* __restrict__ deg, int* __restrict__ rowptr, int n) {
  __shared__ int lds[1024];
  const int t = threadIdx.x;
  const int chunk = (n + 1023) / 1024;
  const int beg = t * chunk;
  const int fin = min(beg + chunk, n);
  int s = 0;
  for (int i = beg; i < fin; ++i) s += deg[i];
  lds[t] = s;
  __syncthreads();
  for (int o = 1; o < 1024; o <<= 1) {
    int v = (t >= o) ? lds[t - o] : 0;
    __syncthreads();
    lds[t] += v;
    __syncthreads();
  }
  int excl = (t == 0) ? 0 : lds[t - 1];
  for (int i = beg; i < fin; ++i) {
    rowptr[i] = excl;
    excl += deg[i];
  }
  if (t == 1023) rowptr[n] = lds[1023];
}

// ---------------------------------------------------------------------------
// Pass 3: dinv[i] = rsqrt(deg[i] + 1)
// ---------------------------------------------------------------------------
__global__ __launch_bounds__(256) void dinv_kernel(
    const int* __restrict__ deg, float* __restrict__ dinv, int n) {
  int i = blockIdx.x * 256 + threadIdx.x;
  if (i < n) dinv[i] = rsqrtf((float)deg[i] + 1.0f);
}

// ---------------------------------------------------------------------------
// Pass 4: scatter packed (src, weight) records into CSR order.
// Dense 6.4 MB target region -> L2-resident, writeback ~= region size.
// ---------------------------------------------------------------------------
__global__ __launch_bounds__(256) void scatter_kernel(
    const int* __restrict__ src, const int* __restrict__ dst,
    const int* __restrict__ slot, const int* __restrict__ rowptr,
    const float* __restrict__ dinv, int2* __restrict__ edges, int E) {
  int e = blockIdx.x * 256 + threadIdx.x;
  if (e >= E) return;
  int d = dst[e];
  int s = src[e];
  int pos = rowptr[d] + slot[e];
  float w = dinv[s] * dinv[d];
  int2 v;
  v.x = s;
  v.y = __float_as_int(w);
  edges[pos] = v;
}

// ---------------------------------------------------------------------------
// FP32 GEMM  C[M,NCOL] = A[M,128] * W[128,NCOL], bf16 output.
// BM=64, BN=64, BK=16, 256 threads, 4x4 micro-tile.
// ---------------------------------------------------------------------------
template <int NCOL>
__global__ __launch_bounds__(256) void gemm_k128_kernel(
    const float* __restrict__ A, const float* __restrict__ W,
    unsigned short* __restrict__ C, int M) {
  constexpr int BK = 16;
  constexpr int PAD = 68;
  __shared__ float As[BK][PAD];
  __shared__ float Ws[BK][PAD];

  const int tid = threadIdx.x;
  const int tc = tid & 15;
  const int tr = tid >> 4;
  const int m0 = blockIdx.x * 64;
  const int n0 = (NCOL > 64) ? (blockIdx.y * 64) : 0;

  const int arow = tid >> 2;
  const int akq = (tid & 3) * 4;
  const int grow = m0 + arow;
  const int wk = tid >> 4;
  const int wc = (tid & 15) * 4;

  float acc[4][4] = {};

  for (int k0 = 0; k0 < 128; k0 += BK) {
    float4 av = make_float4(0.f, 0.f, 0.f, 0.f);
    if (grow < M) av = *(const float4*)(A + (size_t)grow * 128 + k0 + akq);
    float4 wv = *(const float4*)(W + (size_t)(k0 + wk) * NCOL + n0 + wc);
    __syncthreads();
    As[akq + 0][arow] = av.x;
    As[akq + 1][arow] = av.y;
    As[akq + 2][arow] = av.z;
    As[akq + 3][arow] = av.w;
    *(float4*)&Ws[wk][wc] = wv;
    __syncthreads();
#pragma unroll
    for (int k = 0; k < BK; ++k) {
      float4 a4 = *(const float4*)&As[k][tr * 4];
      float4 b4 = *(const float4*)&Ws[k][tc * 4];
      float a[4] = {a4.x, a4.y, a4.z, a4.w};
      float b[4] = {b4.x, b4.y, b4.z, b4.w};
#pragma unroll
      for (int i = 0; i < 4; ++i)
#pragma unroll
        for (int j = 0; j < 4; ++j) acc[i][j] += a[i] * b[j];
    }
  }

#pragma unroll
  for (int i = 0; i < 4; ++i) {
    int r = m0 + tr * 4 + i;
    if (r < M) {
      ushort4 u;
      u.x = f2bf(acc[i][0]);
      u.y = f2bf(acc[i][1]);
      u.z = f2bf(acc[i][2]);
      u.w = f2bf(acc[i][3]);
      *(ushort4*)(C + (size_t)r * NCOL + n0 + tc * 4) = u;
    }
  }
}

// ---------------------------------------------------------------------------
// Aggregation (CSR): one wave per node, bf16 h input, fp32 out.
// 8-wide unroll: 8 independent packed-edge loads + 8 independent row-gathers.
// ---------------------------------------------------------------------------
template <int COLS>
__global__ __launch_bounds__(256) void aggregate_kernel(
    const unsigned short* __restrict__ h, const int2* __restrict__ edges,
    const int* __restrict__ rowptr, const float* __restrict__ dinv,
    const float* __restrict__ bias, float* __restrict__ out, int n) {
  const int wave = threadIdx.x >> 6;
  const int lane = threadIdx.x & 63;
  const int nid = blockIdx.x * 4 + wave;
  if (nid >= n) return;

  const float di = dinv[nid];
  int p = rowptr[nid];
  const int end = rowptr[nid + 1];

  if (COLS == 128) {
    const unsigned col = lane * 2;  // two bf16 per lane
    float ax = 0.f, ay = 0.f;
    for (; p + 8 <= end; p += 8) {
      int2 e0 = edges[p + 0], e1 = edges[p + 1], e2 = edges[p + 2], e3 = edges[p + 3];
      int2 e4 = edges[p + 4], e5 = edges[p + 5], e6 = edges[p + 6], e7 = edges[p + 7];
      unsigned v0 = *(const unsigned*)(h + (size_t)e0.x * 128 + col);
      unsigned v1 = *(const unsigned*)(h + (size_t)e1.x * 128 + col);
      unsigned v2 = *(const unsigned*)(h + (size_t)e2.x * 128 + col);
      unsigned v3 = *(const unsigned*)(h + (size_t)e3.x * 128 + col);
      unsigned v4 = *(const unsigned*)(h + (size_t)e4.x * 128 + col);
      unsigned v5 = *(const unsigned*)(h + (size_t)e5.x * 128 + col);
      unsigned v6 = *(const unsigned*)(h + (size_t)e6.x * 128 + col);
      unsigned v7 = *(const unsigned*)(h + (size_t)e7.x * 128 + col);
      float w0 = __int_as_float(e0.y), w1 = __int_as_float(e1.y);
      float w2 = __int_as_float(e2.y), w3 = __int_as_float(e3.y);
      float w4 = __int_as_float(e4.y), w5 = __int_as_float(e5.y);
      float w6 = __int_as_float(e6.y), w7 = __int_as_float(e7.y);
      ax += bf_lo(v0) * w0 + bf_lo(v1) * w1 + bf_lo(v2) * w2 + bf_lo(v3) * w3;
      ay += bf_hi(v0) * w0 + bf_hi(v1) * w1 + bf_hi(v2) * w2 + bf_hi(v3) * w3;
      ax += bf_lo(v4) * w4 + bf_lo(v5) * w5 + bf_lo(v6) * w6 + bf_lo(v7) * w7;
      ay += bf_hi(v4) * w4 + bf_hi(v5) * w5 + bf_hi(v6) * w6 + bf_hi(v7) * w7;
    }
    for (; p < end; ++p) {
      int2 e0 = edges[p];
      float w = __int_as_float(e0.y);
      unsigned v = *(const unsigned*)(h + (size_t)e0.x * 128 + col);
      ax += bf_lo(v) * w;
      ay += bf_hi(v) * w;
    }
    float w2 = di * di;
    unsigned v = *(const unsigned*)(h + (size_t)nid * 128 + col);
    ax += bf_lo(v) * w2;
    ay += bf_hi(v) * w2;
    float2 bv = *(const float2*)(bias + col);
    ax = fmaxf(ax + bv.x, 0.f);
    ay = fmaxf(ay + bv.y, 0.f);
    *(float2*)(out + (size_t)nid * 128 + col) = make_float2(ax, ay);
  } else {  // COLS == 64
    float acc = 0.f;
    for (; p + 8 <= end; p += 8) {
      int2 e0 = edges[p + 0], e1 = edges[p + 1], e2 = edges[p + 2], e3 = edges[p + 3];
      int2 e4 = edges[p + 4], e5 = edges[p + 5], e6 = edges[p + 6], e7 = edges[p + 7];
      unsigned short v0 = h[(size_t)e0.x * 64 + lane];
      unsigned short v1 = h[(size_t)e1.x * 64 + lane];
      unsigned short v2 = h[(size_t)e2.x * 64 + lane];
      unsigned short v3 = h[(size_t)e3.x * 64 + lane];
      unsigned short v4 = h[(size_t)e4.x * 64 + lane];
      unsigned short v5 = h[(size_t)e5.x * 64 + lane];
      unsigned short v6 = h[(size_t)e6.x * 64 + lane];
      unsigned short v7 = h[(size_t)e7.x * 64 + lane];
      acc += bf1(v0) * __int_as_float(e0.y) + bf1(v1) * __int_as_float(e1.y);
      acc += bf1(v2) * __int_as_float(e2.y) + bf1(v3) * __int_as_float(e3.y);
      acc += bf1(v4) * __int_as_float(e4.y) + bf1(v5) * __int_as_float(e5.y);
      acc += bf1(v6) * __int_as_float(e6.y) + bf1(v7) * __int_as_float(e7.y);
    }
    for (; p < end; ++p) {
      int2 e0 = edges[p];
      acc += bf1(h[(size_t)e0.x * 64 + lane]) * __int_as_float(e0.y);
    }
    acc += bf1(h[(size_t)nid * 64 + lane]) * di * di;
    acc = fmaxf(acc + bias[lane], 0.f);
    out[(size_t)nid * 64 + lane] = acc;
  }
}

// ---------------------------------------------------------------------------
extern "C" void kernel_launch(void* const* d_in, const int* in_sizes, int n_in,
                              void* d_out, int out_size, void* d_ws, size_t ws_size,
                              hipStream_t stream) {
  const float* x = (const float*)d_in[0];
  const int* edge = (const int*)d_in[1];
  const float* W1 = (const float*)d_in[2];
  const float* b1 = (const float*)d_in[3];
  const float* W2 = (const float*)d_in[4];
  const float* b2 = (const float*)d_in[5];
  float* out = (float*)d_out;

  const int N = in_sizes[0] / DIN;
  const int E = in_sizes[1] / 2;
  const int* src = edge;
  const int* dst = edge + E;

  char* base = (char*)d_ws;
  size_t off = 0;
  auto carve = [&](size_t bytes) {
    char* p = base + off;
    off += (bytes + 255) & ~(size_t)255;
    return p;
  };
  int* deg = (int*)carve((size_t)N * 4);
  float* dinv = (float*)carve((size_t)N * 4);
  int* rowptr = (int*)carve((size_t)(N + 1) * 4);
  int* slot = (int*)carve((size_t)E * 4);
  int2* edges = (int2*)carve((size_t)E * 8);
  unsigned short* h1 = (unsigned short*)carve((size_t)N * DHID * 2);  // bf16
  float* hb = (float*)carve((size_t)N * DHID * 4);                    // fp32
  unsigned short* h2t = h1;  // alias: h1 dead after aggregate1

  hipMemsetAsync(deg, 0, (size_t)N * 4, stream);

  count_kernel<<<(E + 255) / 256, 256, 0, stream>>>(dst, deg, slot, E);
  scan_kernel<<<1, 1024, 0, stream>>>(deg, rowptr, N);
  dinv_kernel<<<(N + 255) / 256, 256, 0, stream>>>(deg, dinv, N);
  scatter_kernel<<<(E + 255) / 256, 256, 0, stream>>>(src, dst, slot, rowptr, dinv, edges, E);

  // layer 1
  {
    dim3 grid((N + 63) / 64, 2);
    gemm_k128_kernel<DHID><<<grid, 256, 0, stream>>>(x, W1, h1, N);
  }
  aggregate_kernel<DHID><<<(N + 3) / 4, 256, 0, stream>>>(h1, edges, rowptr, dinv, b1, hb, N);

  // layer 2
  {
    dim3 grid((N + 63) / 64, 1);
    gemm_k128_kernel<DOUT><<<grid, 256, 0, stream>>>(hb, W2, h2t, N);
  }
  aggregate_kernel<DOUT><<<(N + 3) / 4, 256, 0, stream>>>(h2t, edges, rowptr, dinv, b2, out, N);
}

// Round 4
// 261.822 us; speedup vs baseline: 1.2598x; 1.2598x over previous
//
#include <hip/hip_runtime.h>

#define NNODES 50000
#define NEDGES 800000
#define DIN 128
#define DHID 128
#define DOUT 64

// ---- bf16 helpers ---------------------------------------------------------
static __device__ __forceinline__ unsigned short f2bf(float f) {
  union { float f; unsigned u; } v; v.f = f;
  unsigned r = v.u + 0x7fffu + ((v.u >> 16) & 1u);  // round-nearest-even
  return (unsigned short)(r >> 16);
}
static __device__ __forceinline__ float bf_lo(unsigned v) {
  union { unsigned u; float f; } t; t.u = v << 16; return t.f;
}
static __device__ __forceinline__ float bf_hi(unsigned v) {
  union { unsigned u; float f; } t; t.u = v & 0xffff0000u; return t.f;
}
static __device__ __forceinline__ float bf1(unsigned short v) {
  union { unsigned u; float f; } t; t.u = ((unsigned)v) << 16; return t.f;
}

// ---------------------------------------------------------------------------
// Pass 1: degree count + per-edge slot (dense write by edge index).
// ---------------------------------------------------------------------------
__global__ __launch_bounds__(256) void count_kernel(
    const int* __restrict__ dst, int* __restrict__ deg,
    int* __restrict__ slot, int E) {
  int e = blockIdx.x * 256 + threadIdx.x;
  if (e >= E) return;
  slot[e] = atomicAdd(&deg[dst[e]], 1);
}

// ---------------------------------------------------------------------------
// Pass 2a: per-block (256-elem) local exclusive scan of deg -> rowptr,
// block totals -> bsum. Fuses dinv = rsqrt(deg+1).
// ---------------------------------------------------------------------------
__global__ __launch_bounds__(256) void scan_local_kernel(
    const int* __restrict__ deg, int* __restrict__ rowptr,
    int* __restrict__ bsum, float* __restrict__ dinv, int n) {
  __shared__ int lds[256];
  const int t = threadIdx.x;
  const int i = blockIdx.x * 256 + t;
  int v = (i < n) ? deg[i] : 0;
  if (i < n) dinv[i] = rsqrtf((float)v + 1.0f);
  lds[t] = v;
  __syncthreads();
#pragma unroll
  for (int o = 1; o < 256; o <<= 1) {
    int u = (t >= o) ? lds[t - o] : 0;
    __syncthreads();
    lds[t] += u;
    __syncthreads();
  }
  if (i < n) rowptr[i] = lds[t] - v;  // exclusive within block
  if (t == 255) bsum[blockIdx.x] = lds[255];
}

// ---------------------------------------------------------------------------
// Pass 2b: exclusive scan of block sums (nblocks <= 256), single block.
// ---------------------------------------------------------------------------
__global__ __launch_bounds__(256) void scan_bsum_kernel(
    int* __restrict__ bsum, int nblocks) {
  __shared__ int lds[256];
  const int t = threadIdx.x;
  int v = (t < nblocks) ? bsum[t] : 0;
  lds[t] = v;
  __syncthreads();
#pragma unroll
  for (int o = 1; o < 256; o <<= 1) {
    int u = (t >= o) ? lds[t - o] : 0;
    __syncthreads();
    lds[t] += u;
    __syncthreads();
  }
  if (t < nblocks) bsum[t] = lds[t] - v;  // exclusive
}

// ---------------------------------------------------------------------------
// Pass 2c: add scanned block offsets; rowptr[n] = E (total degree == E).
// ---------------------------------------------------------------------------
__global__ __launch_bounds__(256) void scan_add_kernel(
    int* __restrict__ rowptr, const int* __restrict__ bsum, int n, int E) {
  int i = blockIdx.x * 256 + threadIdx.x;
  if (i < n) rowptr[i] += bsum[i >> 8];
  if (i == n) rowptr[n] = E;
}

// ---------------------------------------------------------------------------
// Pass 3: scatter packed (src, weight) records into CSR order.
// ---------------------------------------------------------------------------
__global__ __launch_bounds__(256) void scatter_kernel(
    const int* __restrict__ src, const int* __restrict__ dst,
    const int* __restrict__ slot, const int* __restrict__ rowptr,
    const float* __restrict__ dinv, int2* __restrict__ edges, int E) {
  int e = blockIdx.x * 256 + threadIdx.x;
  if (e >= E) return;
  int d = dst[e];
  int s = src[e];
  int pos = rowptr[d] + slot[e];
  float w = dinv[s] * dinv[d];
  int2 v;
  v.x = s;
  v.y = __float_as_int(w);
  edges[pos] = v;
}

// ---------------------------------------------------------------------------
// FP32 GEMM  C[M,NCOL] = A[M,128] * W[128,NCOL], bf16 output.
// BM=64, BN=64, BK=16, 256 threads, 4x4 micro-tile.
// ---------------------------------------------------------------------------
template <int NCOL>
__global__ __launch_bounds__(256) void gemm_k128_kernel(
    const float* __restrict__ A, const float* __restrict__ W,
    unsigned short* __restrict__ C, int M) {
  constexpr int BK = 16;
  constexpr int PAD = 68;
  __shared__ float As[BK][PAD];
  __shared__ float Ws[BK][PAD];

  const int tid = threadIdx.x;
  const int tc = tid & 15;
  const int tr = tid >> 4;
  const int m0 = blockIdx.x * 64;
  const int n0 = (NCOL > 64) ? (blockIdx.y * 64) : 0;

  const int arow = tid >> 2;
  const int akq = (tid & 3) * 4;
  const int grow = m0 + arow;
  const int wk = tid >> 4;
  const int wc = (tid & 15) * 4;

  float acc[4][4] = {};

  for (int k0 = 0; k0 < 128; k0 += BK) {
    float4 av = make_float4(0.f, 0.f, 0.f, 0.f);
    if (grow < M) av = *(const float4*)(A + (size_t)grow * 128 + k0 + akq);
    float4 wv = *(const float4*)(W + (size_t)(k0 + wk) * NCOL + n0 + wc);
    __syncthreads();
    As[akq + 0][arow] = av.x;
    As[akq + 1][arow] = av.y;
    As[akq + 2][arow] = av.z;
    As[akq + 3][arow] = av.w;
    *(float4*)&Ws[wk][wc] = wv;
    __syncthreads();
#pragma unroll
    for (int k = 0; k < BK; ++k) {
      float4 a4 = *(const float4*)&As[k][tr * 4];
      float4 b4 = *(const float4*)&Ws[k][tc * 4];
      float a[4] = {a4.x, a4.y, a4.z, a4.w};
      float b[4] = {b4.x, b4.y, b4.z, b4.w};
#pragma unroll
      for (int i = 0; i < 4; ++i)
#pragma unroll
        for (int j = 0; j < 4; ++j) acc[i][j] += a[i] * b[j];
    }
  }

#pragma unroll
  for (int i = 0; i < 4; ++i) {
    int r = m0 + tr * 4 + i;
    if (r < M) {
      ushort4 u;
      u.x = f2bf(acc[i][0]);
      u.y = f2bf(acc[i][1]);
      u.z = f2bf(acc[i][2]);
      u.w = f2bf(acc[i][3]);
      *(ushort4*)(C + (size_t)r * NCOL + n0 + tc * 4) = u;
    }
  }
}

// ---------------------------------------------------------------------------
// Aggregation (CSR): one wave per node, bf16 h input, fp32 out.
// 8-wide unroll: 8 independent packed-edge loads + 8 independent row-gathers.
// ---------------------------------------------------------------------------
template <int COLS>
__global__ __launch_bounds__(256) void aggregate_kernel(
    const unsigned short* __restrict__ h, const int2* __restrict__ edges,
    const int* __restrict__ rowptr, const float* __restrict__ dinv,
    const float* __restrict__ bias, float* __restrict__ out, int n) {
  const int wave = threadIdx.x >> 6;
  const int lane = threadIdx.x & 63;
  const int nid = blockIdx.x * 4 + wave;
  if (nid >= n) return;

  const float di = dinv[nid];
  int p = rowptr[nid];
  const int end = rowptr[nid + 1];

  if (COLS == 128) {
    const unsigned col = lane * 2;
    float ax = 0.f, ay = 0.f;
    for (; p + 8 <= end; p += 8) {
      int2 e0 = edges[p + 0], e1 = edges[p + 1], e2 = edges[p + 2], e3 = edges[p + 3];
      int2 e4 = edges[p + 4], e5 = edges[p + 5], e6 = edges[p + 6], e7 = edges[p + 7];
      unsigned v0 = *(const unsigned*)(h + (size_t)e0.x * 128 + col);
      unsigned v1 = *(const unsigned*)(h + (size_t)e1.x * 128 + col);
      unsigned v2 = *(const unsigned*)(h + (size_t)e2.x * 128 + col);
      unsigned v3 = *(const unsigned*)(h + (size_t)e3.x * 128 + col);
      unsigned v4 = *(const unsigned*)(h + (size_t)e4.x * 128 + col);
      unsigned v5 = *(const unsigned*)(h + (size_t)e5.x * 128 + col);
      unsigned v6 = *(const unsigned*)(h + (size_t)e6.x * 128 + col);
      unsigned v7 = *(const unsigned*)(h + (size_t)e7.x * 128 + col);
      float w0 = __int_as_float(e0.y), w1 = __int_as_float(e1.y);
      float w2 = __int_as_float(e2.y), w3 = __int_as_float(e3.y);
      float w4 = __int_as_float(e4.y), w5 = __int_as_float(e5.y);
      float w6 = __int_as_float(e6.y), w7 = __int_as_float(e7.y);
      ax += bf_lo(v0) * w0 + bf_lo(v1) * w1 + bf_lo(v2) * w2 + bf_lo(v3) * w3;
      ay += bf_hi(v0) * w0 + bf_hi(v1) * w1 + bf_hi(v2) * w2 + bf_hi(v3) * w3;
      ax += bf_lo(v4) * w4 + bf_lo(v5) * w5 + bf_lo(v6) * w6 + bf_lo(v7) * w7;
      ay += bf_hi(v4) * w4 + bf_hi(v5) * w5 + bf_hi(v6) * w6 + bf_hi(v7) * w7;
    }
    for (; p < end; ++p) {
      int2 e0 = edges[p];
      float w = __int_as_float(e0.y);
      unsigned v = *(const unsigned*)(h + (size_t)e0.x * 128 + col);
      ax += bf_lo(v) * w;
      ay += bf_hi(v) * w;
    }
    float w2 = di * di;
    unsigned v = *(const unsigned*)(h + (size_t)nid * 128 + col);
    ax += bf_lo(v) * w2;
    ay += bf_hi(v) * w2;
    float2 bv = *(const float2*)(bias + col);
    ax = fmaxf(ax + bv.x, 0.f);
    ay = fmaxf(ay + bv.y, 0.f);
    *(float2*)(out + (size_t)nid * 128 + col) = make_float2(ax, ay);
  } else {
    float acc = 0.f;
    for (; p + 8 <= end; p += 8) {
      int2 e0 = edges[p + 0], e1 = edges[p + 1], e2 = edges[p + 2], e3 = edges[p + 3];
      int2 e4 = edges[p + 4], e5 = edges[p + 5], e6 = edges[p + 6], e7 = edges[p + 7];
      unsigned short v0 = h[(size_t)e0.x * 64 + lane];
      unsigned short v1 = h[(size_t)e1.x * 64 + lane];
      unsigned short v2 = h[(size_t)e2.x * 64 + lane];
      unsigned short v3 = h[(size_t)e3.x * 64 + lane];
      unsigned short v4 = h[(size_t)e4.x * 64 + lane];
      unsigned short v5 = h[(size_t)e5.x * 64 + lane];
      unsigned short v6 = h[(size_t)e6.x * 64 + lane];
      unsigned short v7 = h[(size_t)e7.x * 64 + lane];
      acc += bf1(v0) * __int_as_float(e0.y) + bf1(v1) * __int_as_float(e1.y);
      acc += bf1(v2) * __int_as_float(e2.y) + bf1(v3) * __int_as_float(e3.y);
      acc += bf1(v4) * __int_as_float(e4.y) + bf1(v5) * __int_as_float(e5.y);
      acc += bf1(v6) * __int_as_float(e6.y) + bf1(v7) * __int_as_float(e7.y);
    }
    for (; p < end; ++p) {
      int2 e0 = edges[p];
      acc += bf1(h[(size_t)e0.x * 64 + lane]) * __int_as_float(e0.y);
    }
    acc += bf1(h[(size_t)nid * 64 + lane]) * di * di;
    acc = fmaxf(acc + bias[lane], 0.f);
    out[(size_t)nid * 64 + lane] = acc;
  }
}

// ---------------------------------------------------------------------------
extern "C" void kernel_launch(void* const* d_in, const int* in_sizes, int n_in,
                              void* d_out, int out_size, void* d_ws, size_t ws_size,
                              hipStream_t stream) {
  const float* x = (const float*)d_in[0];
  const int* edge = (const int*)d_in[1];
  const float* W1 = (const float*)d_in[2];
  const float* b1 = (const float*)d_in[3];
  const float* W2 = (const float*)d_in[4];
  const float* b2 = (const float*)d_in[5];
  float* out = (float*)d_out;

  const int N = in_sizes[0] / DIN;
  const int E = in_sizes[1] / 2;
  const int* src = edge;
  const int* dst = edge + E;

  char* base = (char*)d_ws;
  size_t off = 0;
  auto carve = [&](size_t bytes) {
    char* p = base + off;
    off += (bytes + 255) & ~(size_t)255;
    return p;
  };
  int* deg = (int*)carve((size_t)N * 4);
  float* dinv = (float*)carve((size_t)N * 4);
  int* rowptr = (int*)carve((size_t)(N + 1) * 4);
  int* bsum = (int*)carve(256 * 4);
  int* slot = (int*)carve((size_t)E * 4);
  int2* edges = (int2*)carve((size_t)E * 8);
  unsigned short* h1 = (unsigned short*)carve((size_t)N * DHID * 2);  // bf16
  float* hb = (float*)carve((size_t)N * DHID * 4);                    // fp32
  unsigned short* h2t = h1;  // alias: h1 dead after aggregate1

  const int nblocks = (N + 255) / 256;  // 196 <= 256

  hipMemsetAsync(deg, 0, (size_t)N * 4, stream);

  count_kernel<<<(E + 255) / 256, 256, 0, stream>>>(dst, deg, slot, E);
  scan_local_kernel<<<nblocks, 256, 0, stream>>>(deg, rowptr, bsum, dinv, N);
  scan_bsum_kernel<<<1, 256, 0, stream>>>(bsum, nblocks);
  scan_add_kernel<<<(N + 256) / 256, 256, 0, stream>>>(rowptr, bsum, N, E);
  scatter_kernel<<<(E + 255) / 256, 256, 0, stream>>>(src, dst, slot, rowptr, dinv, edges, E);

  // layer 1
  {
    dim3 grid((N + 63) / 64, 2);
    gemm_k128_kernel<DHID><<<grid, 256, 0, stream>>>(x, W1, h1, N);
  }
  aggregate_kernel<DHID><<<(N + 3) / 4, 256, 0, stream>>>(h1, edges, rowptr, dinv, b1, hb, N);

  // layer 2
  {
    dim3 grid((N + 63) / 64, 1);
    gemm_k128_kernel<DOUT><<<grid, 256, 0, stream>>>(hb, W2, h2t, N);
  }
  aggregate_kernel<DOUT><<<(N + 3) / 4, 256, 0, stream>>>(h2t, edges, rowptr, dinv, b2, out, N);
}